// Round 15
// baseline (501.971 us; speedup 1.0000x reference)
//
#include <hip/hip_runtime.h>
#include <hip/hip_bf16.h>
#include <stdint.h>

#define B_ 8
#define T_ 10
#define N_ 50
#define IN_ 6
#define H_ 256
#define K_ 4
#define E_ 2450
#define ROWS 400           // B_*N_
#define APB 102400         // elements per ty-slice of aggPB (400 rows x 256)

typedef __attribute__((ext_vector_type(8))) __bf16 bf16x8;
typedef __attribute__((ext_vector_type(4))) float f32x4;

__device__ __forceinline__ unsigned short f2bf(float x) {
    unsigned int u = __float_as_uint(x);
    u = (u + 0x7fffu + ((u >> 16) & 1u)) >> 16;   // RNE
    return (unsigned short)u;
}
__device__ __forceinline__ unsigned pk2(float a, float b) {
    return (unsigned)f2bf(a) | ((unsigned)f2bf(b) << 16);
}
__device__ __forceinline__ float bf2f(unsigned short v) {
    return __uint_as_float((unsigned)v << 16);
}
__device__ __forceinline__ float rcp_fast(float x) { return __builtin_amdgcn_rcpf(x); }
__device__ __forceinline__ float tanh_fast(float x) {
    float e = __expf(2.0f * x);
    return 1.0f - 2.0f * rcp_fast(e + 1.0f);
}
__device__ __forceinline__ float sigmoid_fast(float x) {
    return rcp_fast(1.0f + __expf(-x));
}

// Swizzle: w1s | w2s | gws | wos | zero hidden0 | init UV(t=0) (hidden=0 -> U=b1,V=0).
__global__ __launch_bounds__(256) void swizzle_weights(
        const float* __restrict__ w1, const float* __restrict__ w2,
        const float* __restrict__ whr, const float* __restrict__ whi,
        const float* __restrict__ whh, const float* __restrict__ wo1,
        const float* __restrict__ wo2, const float* __restrict__ b1,
        unsigned short* __restrict__ w1s, unsigned short* __restrict__ w2s,
        unsigned short* __restrict__ gws, unsigned short* __restrict__ wos,
        unsigned int* __restrict__ hidden_zero, float* __restrict__ UV) {
    const int W1N = 3 * 16 * 16 * 64 * 8;   // 393216
    const int W2N = 3 * 16 * 8 * 64 * 8;    // 196608
    const int GWN = 3 * 65536;              // 196608
    const int WON = 2 * 65536;              // 131072
    const int ZN  = 102400;                 // hidden0 fp32
    int idx = blockIdx.x * 256 + threadIdx.x;
    if (idx < W1N) {
        int j = idx & 7, L = (idx >> 3) & 63, kt = (idx >> 9) & 15;
        int nt = (idx >> 13) & 15, i = idx >> 17;
        int n = nt * 16 + (L & 15);
        int k = kt * 32 + ((L >> 4) << 3) + j;
        w1s[idx] = f2bf(w1[((size_t)(i + 1) * H_ + n) * (2 * H_) + k]);
    } else if (idx < W1N + W2N) {
        int t = idx - W1N;
        int j = t & 7, L = (t >> 3) & 63, kt = (t >> 9) & 7;
        int nt = (t >> 12) & 15, i = t >> 16;
        int n = nt * 16 + (L & 15);
        int k = kt * 32 + ((L >> 4) << 3) + j;
        w2s[t] = f2bf(w2[((size_t)(i + 1) * H_ + n) * H_ + k]);
    } else if (idx < W1N + W2N + GWN) {
        int t = idx - (W1N + W2N);
        int j = t & 7, L = (t >> 3) & 63, kt = (t >> 9) & 7;
        int nt = (t >> 12) & 15, mat = t >> 16;
        int n = nt * 16 + (L & 15);
        int k = kt * 32 + ((L >> 4) << 3) + j;
        const float* src = (mat == 0) ? whr : (mat == 1) ? whi : whh;
        gws[t] = f2bf(src[(size_t)n * H_ + k]);
    } else if (idx < W1N + W2N + GWN + WON) {
        int t = idx - (W1N + W2N + GWN);
        int j = t & 7, L = (t >> 3) & 63, kt = (t >> 9) & 7;
        int nt = (t >> 12) & 15, g = t >> 16;
        int n = nt * 16 + (L & 15);
        int k = kt * 32 + ((L >> 4) << 3) + j;
        const float* src = (g == 0) ? wo1 : wo2;
        wos[t] = f2bf(src[(size_t)n * H_ + k]);
    } else if (idx < W1N + W2N + GWN + WON + ZN) {
        hidden_zero[idx - (W1N + W2N + GWN + WON)] = 0u;
    } else {
        // UV(0): hidden == 0 -> U = b1 (folded), V = 0. Linear elem of UV.
        int t = idx - (W1N + W2N + GWN + WON + ZN);   // [0, 614400)
        int c = t & 511;
        int ty = (t >> 9) % 3;
        UV[t] = (c < 256) ? b1[(ty + 1) * H_ + c] : 0.0f;
    }
}

// Fused m1-build + GEMM2 + sender-reduction. Block = (ty, b, recv r), 1200
// blocks (proven R0-R10 structure). Final store writes a bf16 PARTIAL
// (scaled 1/147) in nodeuv's A-frag layout at slice ty*APB.
__global__ __launch_bounds__(256, 4) void msgagg_kernel(
        const float* __restrict__ UV, const float* __restrict__ edges,
        const unsigned short* __restrict__ w2s,
        const float* __restrict__ b2, unsigned short* __restrict__ aggPB, int t) {
    __shared__ unsigned short m1F[32 * 512];
    __shared__ float relS[64];

    int ty = blockIdx.x / 400;
    int rem = blockIdx.x - ty * 400;
    int b = rem / 50;
    int r = rem - b * 50;
    int tid = threadIdx.x;
    int lane = tid & 63, wid = tid >> 6;
    int col = lane & 15, q = lane >> 4;

    if (tid < 64) {
        float v = 0.0f;
        if (tid < 50 && tid != r) {
            int e = tid * 49 + (r > tid ? r - 1 : r);
            v = edges[(((size_t)b * T_ + t) * E_ + e) * K_ + ty + 1];
        }
        relS[tid] = v;
    }

    {
        // rows >= 50 and row == r produce garbage-but-bounded values; their
        // contribution is killed by relS[row] == 0 in the epilogue.
        int row = wid * 16 + col;
        int sv = row < N_ ? row : N_ - 1;
        const float* Vrow = &UV[((size_t)(b * N_ + sv) * 3 + ty) * 512 + 256 + q * 8];
        const float* Urow = &UV[((size_t)(b * N_ + r) * 3 + ty) * 512 + q * 8];
        #pragma unroll
        for (int kt = 0; kt < 8; ++kt) {
            float4 v0 = *(const float4*)(Vrow + kt * 32);
            float4 v1 = *(const float4*)(Vrow + kt * 32 + 4);
            float4 u0 = *(const float4*)(Urow + kt * 32);
            float4 u1 = *(const float4*)(Urow + kt * 32 + 4);
            float m0 = tanh_fast(u0.x + v0.x);
            float m1 = tanh_fast(u0.y + v0.y);
            float m2 = tanh_fast(u0.z + v0.z);
            float m3 = tanh_fast(u0.w + v0.w);
            float m4 = tanh_fast(u1.x + v1.x);
            float m5 = tanh_fast(u1.y + v1.y);
            float m6 = tanh_fast(u1.z + v1.z);
            float m7 = tanh_fast(u1.w + v1.w);
            uint4 pk;
            pk.x = pk2(m0, m1); pk.y = pk2(m2, m3);
            pk.z = pk2(m4, m5); pk.w = pk2(m6, m7);
            *(uint4*)&m1F[(wid * 8 + kt) * 512 + lane * 8] = pk;
        }
    }
    __syncthreads();

    const bf16x8* w2f = (const bf16x8*)w2s;
    f32x4 acc[4][4];
    #pragma unroll
    for (int mt = 0; mt < 4; ++mt)
        #pragma unroll
        for (int u = 0; u < 4; ++u) acc[mt][u] = (f32x4){0.f, 0.f, 0.f, 0.f};

    #pragma unroll
    for (int kt = 0; kt < 8; ++kt) {
        bf16x8 a0 = *(const bf16x8*)&m1F[(0 * 8 + kt) * 512 + lane * 8];
        bf16x8 a1 = *(const bf16x8*)&m1F[(1 * 8 + kt) * 512 + lane * 8];
        bf16x8 a2 = *(const bf16x8*)&m1F[(2 * 8 + kt) * 512 + lane * 8];
        bf16x8 a3 = *(const bf16x8*)&m1F[(3 * 8 + kt) * 512 + lane * 8];
        #pragma unroll
        for (int u = 0; u < 4; ++u) {
            bf16x8 w = w2f[(size_t)((ty * 16 + wid * 4 + u) * 8 + kt) * 64 + lane];
            acc[0][u] = __builtin_amdgcn_mfma_f32_16x16x32_bf16(a0, w, acc[0][u], 0, 0, 0);
            acc[1][u] = __builtin_amdgcn_mfma_f32_16x16x32_bf16(a1, w, acc[1][u], 0, 0, 0);
            acc[2][u] = __builtin_amdgcn_mfma_f32_16x16x32_bf16(a2, w, acc[2][u], 0, 0, 0);
            acc[3][u] = __builtin_amdgcn_mfma_f32_16x16x32_bf16(a3, w, acc[3][u], 0, 0, 0);
        }
    }
    int mm = rem >> 4, rl = rem & 15;       // rem == b*50 + r == global row
    #pragma unroll
    for (int u = 0; u < 4; ++u) {
        float bias = b2[(ty + 1) * H_ + (wid * 4 + u) * 16 + col];
        float sum = 0.0f;
        #pragma unroll
        for (int mt = 0; mt < 4; ++mt)
            #pragma unroll
            for (int rg = 0; rg < 4; ++rg) {
                int row = mt * 16 + q * 4 + rg;
                sum += tanh_fast(acc[mt][u][rg] + bias) * relS[row];
            }
        sum += __shfl_xor(sum, 16);
        sum += __shfl_xor(sum, 32);
        if (lane < 16) {
            int h = (wid * 4 + u) * 16 + col;   // col == lane here
            aggPB[(size_t)ty * APB + (size_t)mm * 4096 + (h >> 5) * 512 +
                  (((h >> 3) & 3) * 16 + rl) * 8 + (h & 7)] = f2bf(sum * (1.0f / 147.0f));
        }
    }
}

// Elementwise sum of the 3 bf16 partial slices -> pre-summed aggB (frag layout
// is elementwise-identical across slices). 12800 threads x 8 shorts = 102400.
__global__ __launch_bounds__(128) void aggsum_kernel(
        const unsigned short* __restrict__ aggPB, unsigned short* __restrict__ aggB) {
    int i = (blockIdx.x * 128 + threadIdx.x) * 8;
    uint4 pa = *(const uint4*)&aggPB[i];
    uint4 pb = *(const uint4*)&aggPB[i + APB];
    uint4 pc = *(const uint4*)&aggPB[i + 2 * APB];
    const unsigned short* ua = (const unsigned short*)&pa;
    const unsigned short* ub = (const unsigned short*)&pb;
    const unsigned short* uc = (const unsigned short*)&pc;
    unsigned short rr[8];
    #pragma unroll
    for (int j = 0; j < 8; ++j)
        rr[j] = f2bf(bf2f(ua[j]) + bf2f(ub[j]) + bf2f(uc[j]));
    *(uint4*)&aggB[i] = *(const uint4*)rr;
}

// Merged node+uv, NO inter-block deps (exact R12 structure — the FAST variant).
// Grid = 175 = 25 x 7. All blocks: direct-load PRE-SUMMED agg A-frags (8 KB
// bf16) + gates GEMM + GRU -> hnF. Role 0: o1/o2/o3 + hidden write.
// Roles 1..6: one (ty,half) GEMM1 slice. R10's prefetches retained.
__global__ __launch_bounds__(512) void nodeuv_kernel(
        const float* __restrict__ inputs, const unsigned short* __restrict__ aggB,
        const unsigned short* __restrict__ gws, const unsigned short* __restrict__ wos,
        const unsigned short* __restrict__ w1s,
        const float* __restrict__ hid_rd, float* __restrict__ hid_wr,
        float* __restrict__ UV,
        const float* __restrict__ w_ir, const float* __restrict__ b_ir,
        const float* __restrict__ w_ii, const float* __restrict__ b_ii,
        const float* __restrict__ w_in, const float* __restrict__ b_in,
        const float* __restrict__ b1,
        const float* __restrict__ b_o1, const float* __restrict__ b_o2,
        const float* __restrict__ w_o3, const float* __restrict__ b_o3,
        float* __restrict__ out, int t) {
    __shared__ unsigned short hnF[8 * 512];    // hidden-new A-frags
    __shared__ unsigned short p1F[8 * 512];    // p1 A-frags (role 0 only)
    __shared__ float p2L[16 * 260];            // p2 fp32 (role 0 only)
    __shared__ float insS[16 * 6];

    int role = blockIdx.x / 25;                 // 0..6
    int mm = blockIdx.x - role * 25;            // 0..24
    if (role > 0 && t == T_ - 1) return;        // UV(T) never consumed

    int tid = threadIdx.x;
    int lane = tid & 63, wid = tid >> 6;        // wid 0..7
    int col = lane & 15, q = lane >> 4;

    const float* src = (t == 0) ? inputs : out;
    int tt = (t == 0) ? 0 : (t - 1);

    // ins rows to LDS (consumed after the pre-GRU sync)
    if (tid < 96) {
        int rl = tid / 6, c = tid - rl * 6;
        int row = mm * 16 + rl;
        int b = row / 50, n = row - b * 50;
        insS[rl * 6 + c] = src[(((size_t)b * T_ + tt) * N_ + n) * IN_ + c];
    }

    // agg A-frags: direct coalesced global load (pre-summed bf16 frag layout)
    bf16x8 af[8];
    #pragma unroll
    for (int kt = 0; kt < 8; ++kt)
        af[kt] = *(const bf16x8*)&aggB[(size_t)mm * 4096 + kt * 512 + lane * 8];

    // prefetch 1: hidden-state scalars for the GRU (8 per thread)
    float hpre[2][4];
    #pragma unroll
    for (int u = 0; u < 2; ++u) {
        int h = (wid * 2 + u) * 16 + col;
        #pragma unroll
        for (int rg = 0; rg < 4; ++rg) {
            int row = mm * 16 + q * 4 + rg;
            hpre[u][rg] = hid_rd[(size_t)row * H_ + h];
        }
    }

    // prefetch 2: tail W-frags (role 0: o1; roles>0: own (ty,half) slice)
    const bf16x8* wof = (const bf16x8*)wos;
    const bf16x8* w1f = (const bf16x8*)w1s;
    bf16x8 tw[8][2];
    if (role == 0) {
        #pragma unroll
        for (int kt = 0; kt < 8; ++kt)
            #pragma unroll
            for (int u = 0; u < 2; ++u)
                tw[kt][u] = wof[(size_t)((wid * 2 + u) * 8 + kt) * 64 + lane];
    } else {
        int s = role - 1;
        int ty = s >> 1, half = s & 1;
        #pragma unroll
        for (int kt = 0; kt < 8; ++kt)
            #pragma unroll
            for (int u = 0; u < 2; ++u)
                tw[kt][u] = w1f[(size_t)((ty * 16 + wid * 2 + u) * 16 + half * 8 + kt) * 64 + lane];
    }

    // gates GEMM: double-buffer W-frags in 2-kt chunks (R7 schedule).
    const bf16x8* gwf = (const bf16x8*)gws;
    f32x4 acc[3][2];
    #pragma unroll
    for (int m = 0; m < 3; ++m)
        #pragma unroll
        for (int u = 0; u < 2; ++u) acc[m][u] = (f32x4){0.f, 0.f, 0.f, 0.f};

    bf16x8 wg[2][2][3][2];   // [buf][kt-in-chunk][mat][u]
    #pragma unroll
    for (int ki = 0; ki < 2; ++ki)
        #pragma unroll
        for (int m = 0; m < 3; ++m)
            #pragma unroll
            for (int u = 0; u < 2; ++u)
                wg[0][ki][m][u] = gwf[(size_t)((m * 16 + wid * 2 + u) * 8 + ki) * 64 + lane];
    #pragma unroll
    for (int c = 0; c < 4; ++c) {
        if (c < 3) {
            #pragma unroll
            for (int ki = 0; ki < 2; ++ki)
                #pragma unroll
                for (int m = 0; m < 3; ++m)
                    #pragma unroll
                    for (int u = 0; u < 2; ++u)
                        wg[(c + 1) & 1][ki][m][u] =
                            gwf[(size_t)((m * 16 + wid * 2 + u) * 8 + (c + 1) * 2 + ki) * 64 + lane];
        }
        #pragma unroll
        for (int ki = 0; ki < 2; ++ki)
            #pragma unroll
            for (int m = 0; m < 3; ++m)
                #pragma unroll
                for (int u = 0; u < 2; ++u)
                    acc[m][u] = __builtin_amdgcn_mfma_f32_16x16x32_bf16(
                        af[c * 2 + ki], wg[c & 1][ki][m][u], acc[m][u], 0, 0, 0);
    }
    __syncthreads();   // insS ready for GRU

    // GRU elementwise; all roles compute identical hnF; only role 0 writes hidden.
    #pragma unroll
    for (int u = 0; u < 2; ++u) {
        int h = (wid * 2 + u) * 16 + col;
        float bir = b_ir[h], bii = b_ii[h], bin_ = b_in[h];
        float wir[6], wii[6], win[6];
        #pragma unroll
        for (int c = 0; c < 6; ++c) {
            wir[c] = w_ir[h * 6 + c];
            wii[c] = w_ii[h * 6 + c];
            win[c] = w_in[h * 6 + c];
        }
        #pragma unroll
        for (int rg = 0; rg < 4; ++rg) {
            int rl = q * 4 + rg;
            int row = mm * 16 + rl;
            float xr = bir, xi = bii, xn = bin_;
            #pragma unroll
            for (int c = 0; c < 6; ++c) {
                float iv = insS[rl * 6 + c];
                xr += wir[c] * iv;
                xi += wii[c] * iv;
                xn += win[c] * iv;
            }
            float rgate = sigmoid_fast(xr + acc[0][u][rg]);
            float igate = sigmoid_fast(xi + acc[1][u][rg]);
            float nn = tanh_fast(xn + rgate * acc[2][u][rg]);
            float hnew = (1.0f - igate) * nn + igate * hpre[u][rg];
            if (role == 0) hid_wr[(size_t)row * H_ + h] = hnew;
            hnF[(h >> 5) * 512 + (((h >> 3) & 3) * 16 + rl) * 8 + (h & 7)] = f2bf(hnew);
        }
    }
    __syncthreads();

    if (role > 0) {
        // ---- uv role: GEMM1 slice (ty, half) -> UV(t+1); weights resident in tw ----
        int s = role - 1;
        int ty = s >> 1, half = s & 1;
        bf16x8 a2f[8];
        #pragma unroll
        for (int kt = 0; kt < 8; ++kt)
            a2f[kt] = *(const bf16x8*)&hnF[kt * 512 + lane * 8];
        f32x4 acc2[2];
        #pragma unroll
        for (int u = 0; u < 2; ++u) acc2[u] = (f32x4){0.f, 0.f, 0.f, 0.f};
        #pragma unroll
        for (int kt = 0; kt < 8; ++kt)
            #pragma unroll
            for (int u = 0; u < 2; ++u)
                acc2[u] = __builtin_amdgcn_mfma_f32_16x16x32_bf16(a2f[kt], tw[kt][u], acc2[u], 0, 0, 0);
        #pragma unroll
        for (int u = 0; u < 2; ++u) {
            int nt = wid * 2 + u;
            float bias = (half == 0) ? b1[(ty + 1) * H_ + nt * 16 + col] : 0.0f;
            #pragma unroll
            for (int r = 0; r < 4; ++r)
                UV[((size_t)(mm * 16 + q * 4 + r) * 3 + ty) * 512 + half * 256 +
                   nt * 16 + col] = acc2[u][r] + bias;
        }
        return;
    }

    // ---- role 0: o1 GEMM (weights resident in tw) -> relu -> p1F ----
    {
        bf16x8 a1f[8];
        #pragma unroll
        for (int kt = 0; kt < 8; ++kt)
            a1f[kt] = *(const bf16x8*)&hnF[kt * 512 + lane * 8];
        // o2 W-frags issued now; o1 MFMA + p1F write + sync hide the latency
        bf16x8 o2w[8][2];
        #pragma unroll
        for (int kt = 0; kt < 8; ++kt)
            #pragma unroll
            for (int u = 0; u < 2; ++u)
                o2w[kt][u] = wof[(size_t)((16 + wid * 2 + u) * 8 + kt) * 64 + lane];
        f32x4 a1v[2];
        #pragma unroll
        for (int u = 0; u < 2; ++u) a1v[u] = (f32x4){0.f, 0.f, 0.f, 0.f};
        #pragma unroll
        for (int kt = 0; kt < 8; ++kt)
            #pragma unroll
            for (int u = 0; u < 2; ++u)
                a1v[u] = __builtin_amdgcn_mfma_f32_16x16x32_bf16(a1f[kt], tw[kt][u], a1v[u], 0, 0, 0);
        #pragma unroll
        for (int u = 0; u < 2; ++u) {
            int h = (wid * 2 + u) * 16 + col;
            float bo = b_o1[h];
            #pragma unroll
            for (int rg = 0; rg < 4; ++rg) {
                int rl = q * 4 + rg;
                float v = fmaxf(a1v[u][rg] + bo, 0.0f);
                p1F[(h >> 5) * 512 + (((h >> 3) & 3) * 16 + rl) * 8 + (h & 7)] = f2bf(v);
            }
        }
        __syncthreads();

        // o2 GEMM (weights resident in o2w) -> relu -> p2L
        bf16x8 a2f[8];
        #pragma unroll
        for (int kt = 0; kt < 8; ++kt)
            a2f[kt] = *(const bf16x8*)&p1F[kt * 512 + lane * 8];
        f32x4 a2v[2];
        #pragma unroll
        for (int u = 0; u < 2; ++u) a2v[u] = (f32x4){0.f, 0.f, 0.f, 0.f};
        #pragma unroll
        for (int kt = 0; kt < 8; ++kt)
            #pragma unroll
            for (int u = 0; u < 2; ++u)
                a2v[u] = __builtin_amdgcn_mfma_f32_16x16x32_bf16(a2f[kt], o2w[kt][u], a2v[u], 0, 0, 0);
        #pragma unroll
        for (int u = 0; u < 2; ++u) {
            int h = (wid * 2 + u) * 16 + col;
            float bo = b_o2[h];
            #pragma unroll
            for (int rg = 0; rg < 4; ++rg) {
                int rl = q * 4 + rg;
                p2L[rl * 260 + h] = fmaxf(a2v[u][rg] + bo, 0.0f);
            }
        }
    }
    __syncthreads();

    // o3: out[row][c] = ins + b_o3[c] + p2[row] . w_o3[c]  (8-way k-split,
    // interleaved k = i*32 + part*4 keeps the 8 parts on distinct LDS banks)
    if (tid < 192) {
        int o = tid >> 3;               // 0..23
        int part = tid & 7;
        #pragma unroll
        for (int pass = 0; pass < 4; ++pass) {
            int oo = o + pass * 24;     // 0..95
            int rl = oo / 6, c = oo - rl * 6;
            float acc3 = (part == 0) ? b_o3[c] : 0.0f;
            const float* wrow = &w_o3[c * 256];
            const float* prow = &p2L[rl * 260];
            #pragma unroll
            for (int i = 0; i < 8; ++i) {
                int k = i * 32 + part * 4;
                float4 w = *(const float4*)&wrow[k];
                float4 p = *(const float4*)&p2L[rl * 260 + k];
                acc3 += w.x * p.x + w.y * p.y + w.z * p.z + w.w * p.w;
            }
            acc3 += __shfl_xor(acc3, 1);
            acc3 += __shfl_xor(acc3, 2);
            acc3 += __shfl_xor(acc3, 4);
            if (part == 0) {
                int row = mm * 16 + rl;
                int b = row / 50, n = row - b * 50;
                out[(((size_t)b * T_ + t) * N_ + n) * IN_ + c] = insS[rl * 6 + c] + acc3;
            }
        }
    }
}

extern "C" void kernel_launch(void* const* d_in, const int* in_sizes, int n_in,
                              void* d_out, int out_size, void* d_ws, size_t ws_size,
                              hipStream_t stream) {
    const float* inputs = (const float*)d_in[0];
    const float* edges  = (const float*)d_in[1];
    const float* msg_w1 = (const float*)d_in[2];
    const float* msg_b1 = (const float*)d_in[3];
    const float* msg_w2 = (const float*)d_in[4];
    const float* msg_b2 = (const float*)d_in[5];
    const float* w_hr = (const float*)d_in[6];
    const float* w_hi = (const float*)d_in[7];
    const float* w_hh = (const float*)d_in[8];
    const float* w_ir = (const float*)d_in[9];
    const float* b_ir = (const float*)d_in[10];
    const float* w_ii = (const float*)d_in[11];
    const float* b_ii = (const float*)d_in[12];
    const float* w_in = (const float*)d_in[13];
    const float* b_in = (const float*)d_in[14];
    const float* w_o1 = (const float*)d_in[15];
    const float* b_o1 = (const float*)d_in[16];
    const float* w_o2 = (const float*)d_in[17];
    const float* b_o2 = (const float*)d_in[18];
    const float* w_o3 = (const float*)d_in[19];
    const float* b_o3 = (const float*)d_in[20];
    float* out = (float*)d_out;

    char* ws = (char*)d_ws;
    float* hidden0           = (float*)(ws);                       // 409,600 B
    float* hidden1           = (float*)(ws + 409600);              // 409,600 B
    float* UV                = (float*)(ws + 819200);              // 2,457,600 B
    unsigned short* aggPB    = (unsigned short*)(ws + 3276800);    // 614,400 B (3 bf16 partial frags)
    unsigned short* w1s      = (unsigned short*)(ws + 4505600);    // 786,432 B
    unsigned short* w2s      = (unsigned short*)(ws + 5292032);    // 393,216 B
    unsigned short* gws      = (unsigned short*)(ws + 5685248);    // 393,216 B
    unsigned short* wos      = (unsigned short*)(ws + 6078464);    // 262,144 B
    unsigned short* aggB     = (unsigned short*)(ws + 6340608);    // 204,800 B (pre-summed frags)

    // setup: swizzle + zero hidden0 + init UV(0).
    // items = 393216+196608+196608+131072+102400+614400 = 1,634,304 = 6384*256
    swizzle_weights<<<dim3(6384), dim3(256), 0, stream>>>(
        msg_w1, msg_w2, w_hr, w_hi, w_hh, w_o1, w_o2, msg_b1,
        w1s, w2s, gws, wos, (unsigned int*)hidden0, UV);

    float* hid[2] = {hidden0, hidden1};
    for (int t = 0; t < T_; ++t) {
        msgagg_kernel<<<dim3(1200), dim3(256), 0, stream>>>(
            UV, edges, w2s, msg_b2, aggPB, t);
        aggsum_kernel<<<dim3(100), dim3(128), 0, stream>>>(aggPB, aggB);
        nodeuv_kernel<<<dim3(175), dim3(512), 0, stream>>>(
            inputs, aggB, gws, wos, w1s, hid[t & 1], hid[(t + 1) & 1], UV,
            w_ir, b_ir, w_ii, b_ii, w_in, b_in, msg_b1,
            b_o1, b_o2, w_o3, b_o3, out, t);
    }
}

// Round 16
// 486.753 us; speedup vs baseline: 1.0313x; 1.0313x over previous
//
#include <hip/hip_runtime.h>
#include <hip/hip_bf16.h>
#include <stdint.h>

#define B_ 8
#define T_ 10
#define N_ 50
#define IN_ 6
#define H_ 256
#define K_ 4
#define E_ 2450
#define ROWS 400           // B_*N_
#define AP 102400          // ROWS*H_

typedef __attribute__((ext_vector_type(8))) __bf16 bf16x8;
typedef __attribute__((ext_vector_type(4))) float f32x4;

__device__ __forceinline__ unsigned short f2bf(float x) {
    unsigned int u = __float_as_uint(x);
    u = (u + 0x7fffu + ((u >> 16) & 1u)) >> 16;   // RNE
    return (unsigned short)u;
}
__device__ __forceinline__ unsigned pk2(float a, float b) {
    return (unsigned)f2bf(a) | ((unsigned)f2bf(b) << 16);
}
__device__ __forceinline__ float rcp_fast(float x) { return __builtin_amdgcn_rcpf(x); }
__device__ __forceinline__ float tanh_fast(float x) {
    float e = __expf(2.0f * x);
    return 1.0f - 2.0f * rcp_fast(e + 1.0f);
}
__device__ __forceinline__ float sigmoid_fast(float x) {
    return rcp_fast(1.0f + __expf(-x));
}

// Swizzle: w1s | w2s | gws | wos | zero hidden0 | init UV(t=0) (hidden=0 -> U=b1,V=0).
__global__ __launch_bounds__(256) void swizzle_weights(
        const float* __restrict__ w1, const float* __restrict__ w2,
        const float* __restrict__ whr, const float* __restrict__ whi,
        const float* __restrict__ whh, const float* __restrict__ wo1,
        const float* __restrict__ wo2, const float* __restrict__ b1,
        unsigned short* __restrict__ w1s, unsigned short* __restrict__ w2s,
        unsigned short* __restrict__ gws, unsigned short* __restrict__ wos,
        unsigned int* __restrict__ hidden_zero, float* __restrict__ UV) {
    const int W1N = 3 * 16 * 16 * 64 * 8;   // 393216
    const int W2N = 3 * 16 * 8 * 64 * 8;    // 196608
    const int GWN = 3 * 65536;              // 196608
    const int WON = 2 * 65536;              // 131072
    const int ZN  = 102400;                 // hidden0 fp32
    int idx = blockIdx.x * 256 + threadIdx.x;
    if (idx < W1N) {
        int j = idx & 7, L = (idx >> 3) & 63, kt = (idx >> 9) & 15;
        int nt = (idx >> 13) & 15, i = idx >> 17;
        int n = nt * 16 + (L & 15);
        int k = kt * 32 + ((L >> 4) << 3) + j;
        w1s[idx] = f2bf(w1[((size_t)(i + 1) * H_ + n) * (2 * H_) + k]);
    } else if (idx < W1N + W2N) {
        int t = idx - W1N;
        int j = t & 7, L = (t >> 3) & 63, kt = (t >> 9) & 7;
        int nt = (t >> 12) & 15, i = t >> 16;
        int n = nt * 16 + (L & 15);
        int k = kt * 32 + ((L >> 4) << 3) + j;
        w2s[t] = f2bf(w2[((size_t)(i + 1) * H_ + n) * H_ + k]);
    } else if (idx < W1N + W2N + GWN) {
        int t = idx - (W1N + W2N);
        int j = t & 7, L = (t >> 3) & 63, kt = (t >> 9) & 7;
        int nt = (t >> 12) & 15, mat = t >> 16;
        int n = nt * 16 + (L & 15);
        int k = kt * 32 + ((L >> 4) << 3) + j;
        const float* src = (mat == 0) ? whr : (mat == 1) ? whi : whh;
        gws[t] = f2bf(src[(size_t)n * H_ + k]);
    } else if (idx < W1N + W2N + GWN + WON) {
        int t = idx - (W1N + W2N + GWN);
        int j = t & 7, L = (t >> 3) & 63, kt = (t >> 9) & 7;
        int nt = (t >> 12) & 15, g = t >> 16;
        int n = nt * 16 + (L & 15);
        int k = kt * 32 + ((L >> 4) << 3) + j;
        const float* src = (g == 0) ? wo1 : wo2;
        wos[t] = f2bf(src[(size_t)n * H_ + k]);
    } else if (idx < W1N + W2N + GWN + WON + ZN) {
        hidden_zero[idx - (W1N + W2N + GWN + WON)] = 0u;
    } else {
        // UV(0): hidden == 0 -> U = b1 (folded), V = 0. Linear elem of UV.
        int t = idx - (W1N + W2N + GWN + WON + ZN);   // [0, 614400)
        int c = t & 511;
        int ty = (t >> 9) % 3;
        UV[t] = (c < 256) ? b1[(ty + 1) * H_ + c] : 0.0f;
    }
}

// Fused m1-build + GEMM2 + sender-reduction. Block = (ty, b, recv r).
// Output scaled by 1/147 = (1/3 msg norm) * (1/49 agg norm).
__global__ __launch_bounds__(256, 4) void msgagg_kernel(
        const float* __restrict__ UV, const float* __restrict__ edges,
        const unsigned short* __restrict__ w2s,
        const float* __restrict__ b2, float* __restrict__ aggP, int t) {
    __shared__ unsigned short m1F[32 * 512];
    __shared__ float relS[64];

    int ty = blockIdx.x / 400;
    int rem = blockIdx.x - ty * 400;
    int b = rem / 50;
    int r = rem - b * 50;
    int tid = threadIdx.x;
    int lane = tid & 63, wid = tid >> 6;
    int col = lane & 15, q = lane >> 4;

    if (tid < 64) {
        float v = 0.0f;
        if (tid < 50 && tid != r) {
            int e = tid * 49 + (r > tid ? r - 1 : r);
            v = edges[(((size_t)b * T_ + t) * E_ + e) * K_ + ty + 1];
        }
        relS[tid] = v;
    }

    {
        // rows >= 50 and row == r produce garbage-but-bounded values; their
        // contribution is killed by relS[row] == 0 in the epilogue.
        int row = wid * 16 + col;
        int sv = row < N_ ? row : N_ - 1;
        const float* Vrow = &UV[((size_t)(b * N_ + sv) * 3 + ty) * 512 + 256 + q * 8];
        const float* Urow = &UV[((size_t)(b * N_ + r) * 3 + ty) * 512 + q * 8];
        #pragma unroll
        for (int kt = 0; kt < 8; ++kt) {
            float4 v0 = *(const float4*)(Vrow + kt * 32);
            float4 v1 = *(const float4*)(Vrow + kt * 32 + 4);
            float4 u0 = *(const float4*)(Urow + kt * 32);
            float4 u1 = *(const float4*)(Urow + kt * 32 + 4);
            float m0 = tanh_fast(u0.x + v0.x);
            float m1 = tanh_fast(u0.y + v0.y);
            float m2 = tanh_fast(u0.z + v0.z);
            float m3 = tanh_fast(u0.w + v0.w);
            float m4 = tanh_fast(u1.x + v1.x);
            float m5 = tanh_fast(u1.y + v1.y);
            float m6 = tanh_fast(u1.z + v1.z);
            float m7 = tanh_fast(u1.w + v1.w);
            uint4 pk;
            pk.x = pk2(m0, m1); pk.y = pk2(m2, m3);
            pk.z = pk2(m4, m5); pk.w = pk2(m6, m7);
            *(uint4*)&m1F[(wid * 8 + kt) * 512 + lane * 8] = pk;
        }
    }
    __syncthreads();

    const bf16x8* w2f = (const bf16x8*)w2s;
    f32x4 acc[4][4];
    #pragma unroll
    for (int mt = 0; mt < 4; ++mt)
        #pragma unroll
        for (int u = 0; u < 4; ++u) acc[mt][u] = (f32x4){0.f, 0.f, 0.f, 0.f};

    #pragma unroll
    for (int kt = 0; kt < 8; ++kt) {
        bf16x8 a0 = *(const bf16x8*)&m1F[(0 * 8 + kt) * 512 + lane * 8];
        bf16x8 a1 = *(const bf16x8*)&m1F[(1 * 8 + kt) * 512 + lane * 8];
        bf16x8 a2 = *(const bf16x8*)&m1F[(2 * 8 + kt) * 512 + lane * 8];
        bf16x8 a3 = *(const bf16x8*)&m1F[(3 * 8 + kt) * 512 + lane * 8];
        #pragma unroll
        for (int u = 0; u < 4; ++u) {
            bf16x8 w = w2f[(size_t)((ty * 16 + wid * 4 + u) * 8 + kt) * 64 + lane];
            acc[0][u] = __builtin_amdgcn_mfma_f32_16x16x32_bf16(a0, w, acc[0][u], 0, 0, 0);
            acc[1][u] = __builtin_amdgcn_mfma_f32_16x16x32_bf16(a1, w, acc[1][u], 0, 0, 0);
            acc[2][u] = __builtin_amdgcn_mfma_f32_16x16x32_bf16(a2, w, acc[2][u], 0, 0, 0);
            acc[3][u] = __builtin_amdgcn_mfma_f32_16x16x32_bf16(a3, w, acc[3][u], 0, 0, 0);
        }
    }
    #pragma unroll
    for (int u = 0; u < 4; ++u) {
        float bias = b2[(ty + 1) * H_ + (wid * 4 + u) * 16 + col];
        float sum = 0.0f;
        #pragma unroll
        for (int mt = 0; mt < 4; ++mt)
            #pragma unroll
            for (int rg = 0; rg < 4; ++rg) {
                int row = mt * 16 + q * 4 + rg;
                sum += tanh_fast(acc[mt][u][rg] + bias) * relS[row];
            }
        sum += __shfl_xor(sum, 16);
        sum += __shfl_xor(sum, 32);
        if (lane < 16)
            aggP[(size_t)ty * AP + (size_t)(b * N_ + r) * H_ +
                 (wid * 4 + u) * 16 + col] = sum * (1.0f / 147.0f);
    }
}

// Merged node+uv, NO inter-block deps (R7 structure). Grid = 175 = 25 x 7 roles.
// All blocks: stage aggP + gates GEMM + GRU -> hnF (redundant, identical).
// Role 0: o1/o2/o3 + hidden write. Roles 1..6: one (ty,half) GEMM1 slice.
// hid_rd scalars + tail W-frags prefetched before the GRU VALU phase;
// role-0's o2 W-frags before o1's MFMAs.
__global__ __launch_bounds__(512) void nodeuv_kernel(
        const float* __restrict__ inputs, const float* __restrict__ aggP,
        const unsigned short* __restrict__ gws, const unsigned short* __restrict__ wos,
        const unsigned short* __restrict__ w1s,
        const float* __restrict__ hid_rd, float* __restrict__ hid_wr,
        float* __restrict__ UV,
        const float* __restrict__ w_ir, const float* __restrict__ b_ir,
        const float* __restrict__ w_ii, const float* __restrict__ b_ii,
        const float* __restrict__ w_in, const float* __restrict__ b_in,
        const float* __restrict__ b1,
        const float* __restrict__ b_o1, const float* __restrict__ b_o2,
        const float* __restrict__ w_o3, const float* __restrict__ b_o3,
        float* __restrict__ out, int t) {
    __shared__ unsigned short aggF[8 * 512];   // agg A-frags (16 rows x 256 k)
    __shared__ unsigned short hnF[8 * 512];    // hidden-new A-frags
    __shared__ unsigned short p1F[8 * 512];    // p1 A-frags (role 0 only)
    __shared__ float p2L[16 * 260];            // p2 fp32 (role 0 only)
    __shared__ float insS[16 * 6];

    int role = blockIdx.x / 25;                 // 0..6
    int mm = blockIdx.x - role * 25;            // 0..24
    if (role > 0 && t == T_ - 1) return;        // UV(T) never consumed

    int tid = threadIdx.x;
    int lane = tid & 63, wid = tid >> 6;        // wid 0..7
    int col = lane & 15, q = lane >> 4;

    const float* src = (t == 0) ? inputs : out;
    int tt = (t == 0) ? 0 : (t - 1);

    // stage agg A-frags (sum of 3 partials): 512 slots, one per thread
    {
        int kt = tid >> 6, L = tid & 63;
        int row = mm * 16 + (L & 15);
        int k0 = kt * 32 + ((L >> 4) << 3);
        const float* p = &aggP[(size_t)row * H_ + k0];
        float4 a0 = *(const float4*)(p);
        float4 a1 = *(const float4*)(p + 4);
        float4 b0 = *(const float4*)(p + AP);
        float4 b1v = *(const float4*)(p + AP + 4);
        float4 c0 = *(const float4*)(p + 2 * AP);
        float4 c1 = *(const float4*)(p + 2 * AP + 4);
        uint4 pk;
        pk.x = pk2(a0.x + b0.x + c0.x, a0.y + b0.y + c0.y);
        pk.y = pk2(a0.z + b0.z + c0.z, a0.w + b0.w + c0.w);
        pk.z = pk2(a1.x + b1v.x + c1.x, a1.y + b1v.y + c1.y);
        pk.w = pk2(a1.z + b1v.z + c1.z, a1.w + b1v.w + c1.w);
        *(uint4*)&aggF[(size_t)kt * 512 + L * 8] = pk;
    }
    if (tid < 96) {
        int rl = tid / 6, c = tid - rl * 6;
        int row = mm * 16 + rl;
        int b = row / 50, n = row - b * 50;
        insS[rl * 6 + c] = src[(((size_t)b * T_ + tt) * N_ + n) * IN_ + c];
    }
    __syncthreads();

    // A-frag preload from LDS
    const bf16x8* gwf = (const bf16x8*)gws;
    bf16x8 af[8];
    #pragma unroll
    for (int kt = 0; kt < 8; ++kt)
        af[kt] = *(const bf16x8*)&aggF[kt * 512 + lane * 8];

    // --- prefetch 1: hidden-state scalars for the GRU (8 per thread) ---
    float hpre[2][4];
    #pragma unroll
    for (int u = 0; u < 2; ++u) {
        int h = (wid * 2 + u) * 16 + col;
        #pragma unroll
        for (int rg = 0; rg < 4; ++rg) {
            int row = mm * 16 + q * 4 + rg;
            hpre[u][rg] = hid_rd[(size_t)row * H_ + h];
        }
    }

    // --- prefetch 2: tail W-frags (role 0: o1; roles>0: own (ty,half) slice) ---
    const bf16x8* wof = (const bf16x8*)wos;
    const bf16x8* w1f = (const bf16x8*)w1s;
    bf16x8 tw[8][2];
    if (role == 0) {
        #pragma unroll
        for (int kt = 0; kt < 8; ++kt)
            #pragma unroll
            for (int u = 0; u < 2; ++u)
                tw[kt][u] = wof[(size_t)((wid * 2 + u) * 8 + kt) * 64 + lane];
    } else {
        int s = role - 1;
        int ty = s >> 1, half = s & 1;
        #pragma unroll
        for (int kt = 0; kt < 8; ++kt)
            #pragma unroll
            for (int u = 0; u < 2; ++u)
                tw[kt][u] = w1f[(size_t)((ty * 16 + wid * 2 + u) * 16 + half * 8 + kt) * 64 + lane];
    }

    // gates GEMM: double-buffer W-frags in 2-kt chunks (R7 schedule).
    f32x4 acc[3][2];
    #pragma unroll
    for (int m = 0; m < 3; ++m)
        #pragma unroll
        for (int u = 0; u < 2; ++u) acc[m][u] = (f32x4){0.f, 0.f, 0.f, 0.f};

    bf16x8 wg[2][2][3][2];   // [buf][kt-in-chunk][mat][u]
    #pragma unroll
    for (int ki = 0; ki < 2; ++ki)
        #pragma unroll
        for (int m = 0; m < 3; ++m)
            #pragma unroll
            for (int u = 0; u < 2; ++u)
                wg[0][ki][m][u] = gwf[(size_t)((m * 16 + wid * 2 + u) * 8 + ki) * 64 + lane];
    #pragma unroll
    for (int c = 0; c < 4; ++c) {
        if (c < 3) {
            #pragma unroll
            for (int ki = 0; ki < 2; ++ki)
                #pragma unroll
                for (int m = 0; m < 3; ++m)
                    #pragma unroll
                    for (int u = 0; u < 2; ++u)
                        wg[(c + 1) & 1][ki][m][u] =
                            gwf[(size_t)((m * 16 + wid * 2 + u) * 8 + (c + 1) * 2 + ki) * 64 + lane];
        }
        #pragma unroll
        for (int ki = 0; ki < 2; ++ki)
            #pragma unroll
            for (int m = 0; m < 3; ++m)
                #pragma unroll
                for (int u = 0; u < 2; ++u)
                    acc[m][u] = __builtin_amdgcn_mfma_f32_16x16x32_bf16(
                        af[c * 2 + ki], wg[c & 1][ki][m][u], acc[m][u], 0, 0, 0);
    }

    // GRU elementwise; all roles compute identical hnF; only role 0 writes hidden.
    #pragma unroll
    for (int u = 0; u < 2; ++u) {
        int h = (wid * 2 + u) * 16 + col;
        float bir = b_ir[h], bii = b_ii[h], bin_ = b_in[h];
        float wir[6], wii[6], win[6];
        #pragma unroll
        for (int c = 0; c < 6; ++c) {
            wir[c] = w_ir[h * 6 + c];
            wii[c] = w_ii[h * 6 + c];
            win[c] = w_in[h * 6 + c];
        }
        #pragma unroll
        for (int rg = 0; rg < 4; ++rg) {
            int rl = q * 4 + rg;
            int row = mm * 16 + rl;
            float xr = bir, xi = bii, xn = bin_;
            #pragma unroll
            for (int c = 0; c < 6; ++c) {
                float iv = insS[rl * 6 + c];
                xr += wir[c] * iv;
                xi += wii[c] * iv;
                xn += win[c] * iv;
            }
            float rgate = sigmoid_fast(xr + acc[0][u][rg]);
            float igate = sigmoid_fast(xi + acc[1][u][rg]);
            float nn = tanh_fast(xn + rgate * acc[2][u][rg]);
            float hnew = (1.0f - igate) * nn + igate * hpre[u][rg];
            if (role == 0) hid_wr[(size_t)row * H_ + h] = hnew;
            hnF[(h >> 5) * 512 + (((h >> 3) & 3) * 16 + rl) * 8 + (h & 7)] = f2bf(hnew);
        }
    }
    __syncthreads();

    if (role > 0) {
        // ---- uv role: GEMM1 slice (ty, half) -> UV(t+1); weights resident in tw ----
        int s = role - 1;
        int ty = s >> 1, half = s & 1;
        bf16x8 a2f[8];
        #pragma unroll
        for (int kt = 0; kt < 8; ++kt)
            a2f[kt] = *(const bf16x8*)&hnF[kt * 512 + lane * 8];
        f32x4 acc2[2];
        #pragma unroll
        for (int u = 0; u < 2; ++u) acc2[u] = (f32x4){0.f, 0.f, 0.f, 0.f};
        #pragma unroll
        for (int kt = 0; kt < 8; ++kt)
            #pragma unroll
            for (int u = 0; u < 2; ++u)
                acc2[u] = __builtin_amdgcn_mfma_f32_16x16x32_bf16(a2f[kt], tw[kt][u], acc2[u], 0, 0, 0);
        #pragma unroll
        for (int u = 0; u < 2; ++u) {
            int nt = wid * 2 + u;
            float bias = (half == 0) ? b1[(ty + 1) * H_ + nt * 16 + col] : 0.0f;
            #pragma unroll
            for (int r = 0; r < 4; ++r)
                UV[((size_t)(mm * 16 + q * 4 + r) * 3 + ty) * 512 + half * 256 +
                   nt * 16 + col] = acc2[u][r] + bias;
        }
        return;
    }

    // ---- role 0: o1 GEMM (weights resident in tw) -> relu -> p1F ----
    {
        bf16x8 a1f[8];
        #pragma unroll
        for (int kt = 0; kt < 8; ++kt)
            a1f[kt] = *(const bf16x8*)&hnF[kt * 512 + lane * 8];
        // o2 W-frags issued now; o1 MFMA + p1F write + sync hide the latency
        bf16x8 o2w[8][2];
        #pragma unroll
        for (int kt = 0; kt < 8; ++kt)
            #pragma unroll
            for (int u = 0; u < 2; ++u)
                o2w[kt][u] = wof[(size_t)((16 + wid * 2 + u) * 8 + kt) * 64 + lane];
        f32x4 a1v[2];
        #pragma unroll
        for (int u = 0; u < 2; ++u) a1v[u] = (f32x4){0.f, 0.f, 0.f, 0.f};
        #pragma unroll
        for (int kt = 0; kt < 8; ++kt)
            #pragma unroll
            for (int u = 0; u < 2; ++u)
                a1v[u] = __builtin_amdgcn_mfma_f32_16x16x32_bf16(a1f[kt], tw[kt][u], a1v[u], 0, 0, 0);
        #pragma unroll
        for (int u = 0; u < 2; ++u) {
            int h = (wid * 2 + u) * 16 + col;
            float bo = b_o1[h];
            #pragma unroll
            for (int rg = 0; rg < 4; ++rg) {
                int rl = q * 4 + rg;
                float v = fmaxf(a1v[u][rg] + bo, 0.0f);
                p1F[(h >> 5) * 512 + (((h >> 3) & 3) * 16 + rl) * 8 + (h & 7)] = f2bf(v);
            }
        }
        __syncthreads();

        // o2 GEMM (weights resident in o2w) -> relu -> p2L
        bf16x8 a2f[8];
        #pragma unroll
        for (int kt = 0; kt < 8; ++kt)
            a2f[kt] = *(const bf16x8*)&p1F[kt * 512 + lane * 8];
        f32x4 a2v[2];
        #pragma unroll
        for (int u = 0; u < 2; ++u) a2v[u] = (f32x4){0.f, 0.f, 0.f, 0.f};
        #pragma unroll
        for (int kt = 0; kt < 8; ++kt)
            #pragma unroll
            for (int u = 0; u < 2; ++u)
                a2v[u] = __builtin_amdgcn_mfma_f32_16x16x32_bf16(a2f[kt], o2w[kt][u], a2v[u], 0, 0, 0);
        #pragma unroll
        for (int u = 0; u < 2; ++u) {
            int h = (wid * 2 + u) * 16 + col;
            float bo = b_o2[h];
            #pragma unroll
            for (int rg = 0; rg < 4; ++rg) {
                int rl = q * 4 + rg;
                p2L[rl * 260 + h] = fmaxf(a2v[u][rg] + bo, 0.0f);
            }
        }
    }
    __syncthreads();

    // o3: out[row][c] = ins + b_o3[c] + p2[row] . w_o3[c]  (8-way k-split,
    // interleaved k = i*32 + part*4 keeps the 8 parts on distinct LDS banks)
    if (tid < 192) {
        int o = tid >> 3;               // 0..23
        int part = tid & 7;
        #pragma unroll
        for (int pass = 0; pass < 4; ++pass) {
            int oo = o + pass * 24;     // 0..95
            int rl = oo / 6, c = oo - rl * 6;
            float acc3 = (part == 0) ? b_o3[c] : 0.0f;
            const float* wrow = &w_o3[c * 256];
            const float* prow = &p2L[rl * 260];
            #pragma unroll
            for (int i = 0; i < 8; ++i) {
                int k = i * 32 + part * 4;
                float4 w = *(const float4*)&wrow[k];
                float4 p = *(const float4*)&prow[k];
                acc3 += w.x * p.x + w.y * p.y + w.z * p.z + w.w * p.w;
            }
            acc3 += __shfl_xor(acc3, 1);
            acc3 += __shfl_xor(acc3, 2);
            acc3 += __shfl_xor(acc3, 4);
            if (part == 0) {
                int row = mm * 16 + rl;
                int b = row / 50, n = row - b * 50;
                out[(((size_t)b * T_ + t) * N_ + n) * IN_ + c] = insS[rl * 6 + c] + acc3;
            }
        }
    }
}

extern "C" void kernel_launch(void* const* d_in, const int* in_sizes, int n_in,
                              void* d_out, int out_size, void* d_ws, size_t ws_size,
                              hipStream_t stream) {
    const float* inputs = (const float*)d_in[0];
    const float* edges  = (const float*)d_in[1];
    const float* msg_w1 = (const float*)d_in[2];
    const float* msg_b1 = (const float*)d_in[3];
    const float* msg_w2 = (const float*)d_in[4];
    const float* msg_b2 = (const float*)d_in[5];
    const float* w_hr = (const float*)d_in[6];
    const float* w_hi = (const float*)d_in[7];
    const float* w_hh = (const float*)d_in[8];
    const float* w_ir = (const float*)d_in[9];
    const float* b_ir = (const float*)d_in[10];
    const float* w_ii = (const float*)d_in[11];
    const float* b_ii = (const float*)d_in[12];
    const float* w_in = (const float*)d_in[13];
    const float* b_in = (const float*)d_in[14];
    const float* w_o1 = (const float*)d_in[15];
    const float* b_o1 = (const float*)d_in[16];
    const float* w_o2 = (const float*)d_in[17];
    const float* b_o2 = (const float*)d_in[18];
    const float* w_o3 = (const float*)d_in[19];
    const float* b_o3 = (const float*)d_in[20];
    float* out = (float*)d_out;

    char* ws = (char*)d_ws;
    float* hidden0           = (float*)(ws);                       // 409,600 B
    float* hidden1           = (float*)(ws + 409600);              // 409,600 B
    float* UV                = (float*)(ws + 819200);              // 2,457,600 B
    float* aggP              = (float*)(ws + 3276800);             // 1,228,800 B
    unsigned short* w1s      = (unsigned short*)(ws + 4505600);    // 786,432 B
    unsigned short* w2s      = (unsigned short*)(ws + 5292032);    // 393,216 B
    unsigned short* gws      = (unsigned short*)(ws + 5685248);    // 393,216 B
    unsigned short* wos      = (unsigned short*)(ws + 6078464);    // 262,144 B

    // setup: swizzle + zero hidden0 + init UV(0).
    // items = 393216+196608+196608+131072+102400+614400 = 1,634,304 = 6384*256
    swizzle_weights<<<dim3(6384), dim3(256), 0, stream>>>(
        msg_w1, msg_w2, w_hr, w_hi, w_hh, w_o1, w_o2, msg_b1,
        w1s, w2s, gws, wos, (unsigned int*)hidden0, UV);

    float* hid[2] = {hidden0, hidden1};
    for (int t = 0; t < T_; ++t) {
        msgagg_kernel<<<dim3(1200), dim3(256), 0, stream>>>(
            UV, edges, w2s, msg_b2, aggP, t);
        nodeuv_kernel<<<dim3(175), dim3(512), 0, stream>>>(
            inputs, aggP, gws, wos, w1s, hid[t & 1], hid[(t + 1) & 1], UV,
            w_ir, b_ir, w_ii, b_ii, w_in, b_in, msg_b1,
            b_o1, b_o2, w_o3, b_o3, out, t);
    }
}